// Round 1
// baseline (111.733 us; speedup 1.0000x reference)
//
#include <hip/hip_runtime.h>
#include <hip/hip_fp16.h>
#include <math.h>

// LDR toep_corner via FFT chain, radix-16 registerized FFT (4096 = 16^3).
// out[j,b] = Re ifft( sum_{i,s} Gf_ijs . fft( D . fft( Hf_ijs . Xf_ib ) ) )
// Hf = fft(D.H), Xf = ifft(conj(D).x), Gf = fft(G), D_k = exp(i*pi*k/N).
//
// R14 = R13 (proven 90.5us) + mid occupancy attack:
//  * ldr_mid_k -> __launch_bounds__(256,4): 16 waves/CU (VGPR cap 128), so the
//    1024-block grid runs 4 blocks/CU co-resident instead of 2 rounds of 2.
//    mid is the ONLY kernel with grid > 512; pre(224)/fin(128) get <=1
//    block/CU anyway and stay at (256,2) (no spill risk for them).
//  * sched_barrier(0) fences cap scheduler load-hoisting (the R4/R5/R9 spill
//    mechanism): mid head split 8+8 loads, Y phase split 4+4 iterations.
//  * D-twiddle chains (dstep^k serial cmul, depth 15) replaced by per-k
//    compile-time constants e^{i*pi*k/16}: D_e = e^{i*pi*tid/4096} * c_k.
//    Removes a serial ~90cy dependency; numerically tighter than the chain.
// Fixed cost: ~44us harness fill of 256MB d_ws + restore, not controllable.

#define NFFT  4096
#define NT    256
#define CIN   4
#define COUT  4
#define RANK  4
#define BATCH 32
#define PI_F  3.14159265358979323846f

// cos/sin(pi*k/16), k=0..15 (compile-time folded; matches dstep=e^{i*pi/16}).
constexpr float CP16[16] = {
    1.0000000000000000f,  0.9807852804032304f,  0.9238795325112867f,  0.8314696123025452f,
    0.7071067811865476f,  0.5555702330196022f,  0.3826834323650898f,  0.1950903220161282f,
    0.0000000000000000f, -0.1950903220161282f, -0.3826834323650898f, -0.5555702330196022f,
   -0.7071067811865476f, -0.8314696123025452f, -0.9238795325112867f, -0.9807852804032304f };
constexpr float SP16[16] = {
    0.0000000000000000f,  0.1950903220161282f,  0.3826834323650898f,  0.5555702330196022f,
    0.7071067811865476f,  0.8314696123025452f,  0.9238795325112867f,  0.9807852804032304f,
    1.0000000000000000f,  0.9807852804032304f,  0.9238795325112867f,  0.8314696123025452f,
    0.7071067811865476f,  0.5555702330196022f,  0.3826834323650898f,  0.1950903220161282f };

__device__ __forceinline__ float2 cmul(float2 a, float2 b) {
    return make_float2(a.x*b.x - a.y*b.y, a.x*b.y + a.y*b.x);
}
__device__ __forceinline__ float2 cadd(float2 a, float2 b){ return make_float2(a.x+b.x, a.y+b.y); }
__device__ __forceinline__ float2 csub(float2 a, float2 b){ return make_float2(a.x-b.x, a.y-b.y); }

// LDS bank swizzle (R2-proven: SQ_LDS_BANK_CONFLICT ~ 0).
__device__ __forceinline__ int SW(int e){ return e ^ ((e >> 4) & 15); }

// 16-point DFT in registers, natural order in/out (R2-proven numerics).
template<int SIGN>
__device__ __forceinline__ void dft16(float2 v[16]) {
    const float sgn = (float)SIGN;
    const float C8 = 0.923879532511287f, S8 = 0.382683432365090f, H2 = 0.707106781186548f;
    const float2 w1 = make_float2( C8,  sgn*S8);
    const float2 w2 = make_float2( H2,  sgn*H2);
    const float2 w3 = make_float2( S8,  sgn*C8);
    const float2 w4 = make_float2(0.f,  sgn);
    const float2 w6 = make_float2(-H2,  sgn*H2);
    const float2 w9 = make_float2(-C8, -sgn*S8);
    float2 t[16];
    #pragma unroll
    for (int p = 0; p < 4; ++p) {
        float2 a0 = v[p], a1 = v[p+4], a2 = v[p+8], a3 = v[p+12];
        float2 b0 = cadd(a0,a2), b1 = csub(a0,a2), b2 = cadd(a1,a3), b3 = csub(a1,a3);
        float2 ib3 = make_float2(-sgn*b3.y, sgn*b3.x);   // SIGN*i*b3
        float2 X0 = cadd(b0,b2), X2c = csub(b0,b2);
        float2 X1 = cadd(b1,ib3), X3 = csub(b1,ib3);
        if (p == 1) { X1 = cmul(X1,w1); X2c = cmul(X2c,w2); X3 = cmul(X3,w3); }
        else if (p == 2) { X1 = cmul(X1,w2); X2c = cmul(X2c,w4); X3 = cmul(X3,w6); }
        else if (p == 3) { X1 = cmul(X1,w3); X2c = cmul(X2c,w6); X3 = cmul(X3,w9); }
        t[4*p+0]=X0; t[4*p+1]=X1; t[4*p+2]=X2c; t[4*p+3]=X3;
    }
    #pragma unroll
    for (int q = 0; q < 4; ++q) {
        float2 a0 = t[q], a1 = t[q+4], a2 = t[q+8], a3 = t[q+12];
        float2 b0 = cadd(a0,a2), b1 = csub(a0,a2), b2 = cadd(a1,a3), b3 = csub(a1,a3);
        float2 ib3 = make_float2(-sgn*b3.y, sgn*b3.x);
        v[q+0]  = cadd(b0,b2);
        v[q+8]  = csub(b0,b2);
        v[q+4]  = cadd(b1,ib3);
        v[q+12] = csub(b1,ib3);
    }
}

// v[k] *= e^{i*k*ang}; two independent power chains (depth ~8 not 15).
__device__ __forceinline__ void twiddle16(float2 v[16], float ang) {
    float sn, cs; __sincosf(ang, &sn, &cs);
    float2 w  = make_float2(cs, sn);
    float2 w2 = cmul(w, w);
    float2 to = w;   // odd powers
    float2 te = w2;  // even powers
    v[1] = cmul(v[1], to);
    v[2] = cmul(v[2], te);
    #pragma unroll
    for (int k = 3; k < 16; k += 2) {
        to = cmul(to, w2); v[k] = cmul(v[k], to);
        if (k + 1 < 16) { te = cmul(te, w2); v[k+1] = cmul(v[k+1], te); }
    }
}

// Stockham radix-16, 3 stages, single 32KB buffer (R2-proven).
// Input: v[r] = x[tid + 256r]. Output: v[k] = X[tid + 256k].
// Trailing barrier: lds reusable by caller on exit.
template<int SIGN>
__device__ void fft4096_r16(float2 v[16], float2* lds, int tid) {
    dft16<SIGN>(v);
    twiddle16(v, (float)SIGN * 2.0f * PI_F * (float)tid / 4096.0f);
    #pragma unroll
    for (int k = 0; k < 16; ++k) lds[SW(16*tid + k)] = v[k];
    __syncthreads();
    #pragma unroll
    for (int r = 0; r < 16; ++r) v[r] = lds[SW(tid + 256*r)];
    dft16<SIGN>(v);
    twiddle16(v, (float)SIGN * 2.0f * PI_F * (float)(tid >> 4) / 256.0f);
    __syncthreads();                       // in-place: all reads before any write
    {
        const int q = tid & 15, p = tid >> 4;
        #pragma unroll
        for (int k = 0; k < 16; ++k) lds[SW(q + 256*p + 16*k)] = v[k];
    }
    __syncthreads();
    #pragma unroll
    for (int r = 0; r < 16; ++r) v[r] = lds[SW(tid + 256*r)];
    dft16<SIGN>(v);
    __syncthreads();                       // lds reusable by caller
}

// ---- Kernel A: precompute. grid 224 x 256.
// bid 0..31: Hc pair rows (ONE fft of D.(h0 + i*h1), no unpack needed);
// bid 32..95: Gf rows; bid 96..223: Xf rows.
__global__ __launch_bounds__(NT, 2) void ldr_pre_k(
    const float* __restrict__ x, const float* __restrict__ G, const float* __restrict__ H,
    float2* __restrict__ Hc, float2* __restrict__ Gf, float2* __restrict__ Xf)
{
    __shared__ float2 lds[NFFT];
    const int tid = threadIdx.x;
    const int bid = blockIdx.x;
    float2 v[16];
    if (bid < 32) {
        // Hc[p] = fft(D.(H[2p] + i*H[2p+1])) = Hf[2p] + i*Hf[2p+1]
        const float* h0 = H + (size_t)(2*bid)     * NFFT;
        const float* h1 = H + (size_t)(2*bid + 1) * NFFT;
        float sn, cs; __sincosf(PI_F * (float)tid / (float)NFFT, &sn, &cs);
        const float2 dt = make_float2(cs, sn);
        #pragma unroll
        for (int k = 0; k < 16; ++k) {
            const int e = tid + 256*k;
            const float2 d = cmul(dt, make_float2(CP16[k], SP16[k]));  // e^{i*pi*e/N}
            v[k] = cmul(d, make_float2(h0[e], h1[e]));
        }
        fft4096_r16<-1>(v, lds, tid);
        float2* o = Hc + (size_t)bid * NFFT;
        #pragma unroll
        for (int k = 0; k < 16; ++k) o[tid + 256*k] = v[k];
    } else if (bid < 96) {
        const int row = bid - 32;
        const float* g = G + (size_t)row * NFFT;
        #pragma unroll
        for (int k = 0; k < 16; ++k) v[k] = make_float2(g[tid + 256*k], 0.0f);
        fft4096_r16<-1>(v, lds, tid);
        float2* o = Gf + (size_t)row * NFFT;
        #pragma unroll
        for (int k = 0; k < 16; ++k) o[tid + 256*k] = v[k];
    } else {
        const int row = bid - 96;
        const float* xp = x + (size_t)row * NFFT;
        float sn, cs; __sincosf(PI_F * (float)tid / (float)NFFT, &sn, &cs);
        const float2 dt = make_float2(cs, -sn);                        // conj(D) thread part
        #pragma unroll
        for (int k = 0; k < 16; ++k) {
            const int e = tid + 256*k;
            const float2 d = cmul(dt, make_float2(CP16[k], -SP16[k])); // e^{-i*pi*e/N}
            float xv = xp[e];
            v[k] = make_float2(d.x*xv, d.y*xv);
        }
        fft4096_r16<1>(v, lds, tid);
        const float invn = 1.0f / (float)NFFT;
        float2* o = Xf + (size_t)row * NFFT;
        #pragma unroll
        for (int k = 0; k < 16; ++k) o[tid + 256*k] = make_float2(v[k].x*invn, v[k].y*invn);
    }
}

// ---- Kernel B: middle. grid 1024 = (ij*2 + pr)(32) x b(32); one rank PAIR
// per wg. Input P = Hc[ip].Xf (one cmul/elem — Hc is the packed pair). Two
// full FFTs, no regs live across FFT calls (spill-free shape, R7-proven).
// R14: (256,4) -> 4 blocks/CU co-resident (128KB LDS of 160KB), VGPR cap 128;
// sched_barrier fences keep the scheduler from hoisting whole load sets.
// Hermitian unpack of Z = fft(t0)+i*fft(t1) via mirror staged in LDS.
// Lower-half Y as fp16, DC.x / Nyq.x packed into element 0; plane u = i*2+pr
// (8 planes), row ((u*COUT + j)*BATCH + b), 2048 half2.
__global__ __launch_bounds__(NT, 4) void ldr_mid_k(
    const float2* __restrict__ Hc, const float2* __restrict__ Xf,
    const float2* __restrict__ Gf, __half2* __restrict__ Ph)
{
    __shared__ float2 lds[NFFT];
    const int tid = threadIdx.x;
    const int bid = blockIdx.x;
    const int b   = bid & (BATCH - 1);
    const int ip  = bid >> 5;           // ij*2 + pr, [0,32)
    const int pr  = ip & 1;
    const int ij  = ip >> 1;
    const int i   = ij >> 2;            // COUT = 4
    const int j   = ij & 3;
    const int r0  = ij*RANK + 2*pr;     // G rows s0 = r0, s1 = r0+1
    const float2* xrow = Xf + (size_t)(i*BATCH + b) * NFFT;
    const float2* hc = Hc + (size_t)ip * NFFT;
    const float2* g0 = Gf + (size_t)r0 * NFFT;
    const float2* g1 = g0 + NFFT;

    float2 v[16];
    #pragma unroll
    for (int k = 0; k < 8; ++k) {
        const int e = tid + 256*k;
        v[k] = cmul(hc[e], xrow[e]);    // = (h0+i*h1).x = h0.x + i*(h1.x)
    }
    __builtin_amdgcn_sched_barrier(0);  // cap in-flight loads (VGPR cap 128)
    #pragma unroll
    for (int k = 8; k < 16; ++k) {
        const int e = tid + 256*k;
        v[k] = cmul(hc[e], xrow[e]);
    }
    fft4096_r16<-1>(v, lds, tid);
    {
        // D_e = e^{i*pi*(tid+256k)/4096} = e^{i*pi*tid/4096} * e^{i*pi*k/16}
        float sn, cs; __sincosf(PI_F * (float)tid / (float)NFFT, &sn, &cs);
        const float2 dt = make_float2(cs, sn);
        #pragma unroll
        for (int k = 0; k < 16; ++k) {
            const float2 d = cmul(dt, make_float2(CP16[k], SP16[k]));
            v[k] = cmul(v[k], d);
        }
    }
    fft4096_r16<-1>(v, lds, tid);       // Z = fft(t0) + i*fft(t1); lds free after

    // Stage upper half of Z for mirror access.
    #pragma unroll
    for (int k = 8; k < 16; ++k) lds[SW(tid + 256*k)] = v[k];
    __syncthreads();

    const int u = i*2 + pr;             // plane in [0,8)
    __half2* prow = Ph + (size_t)((u*COUT + j)*BATCH + b) * (NFFT/2);
    #pragma unroll
    for (int k = 0; k < 8; ++k) {
        if (k == 4) __builtin_amdgcn_sched_barrier(0);  // cap g-load hoisting
        const int e = tid + 256*k;
        const float2 Zk = v[k];
        float2 Zm;
        if (e == 0) Zm = Zk;
        else        Zm = lds[SW(4096 - e)];
        const float2 V1 = make_float2(0.5f*(Zk.x + Zm.x), 0.5f*(Zk.y - Zm.y));
        const float2 V2 = make_float2(0.5f*(Zk.y + Zm.y), 0.5f*(Zm.x - Zk.x));
        float2 Y = cadd(cmul(g0[e], V1), cmul(g1[e], V2));
        if (k == 0 && tid == 0) {
            const float2 Zn = v[8];
            const float Ynyq = g0[2048].x * Zn.x + g1[2048].x * Zn.y;
            Y = make_float2(Y.x, Ynyq);      // pack DC.x / Nyq.x
        }
        prow[e] = __floats2half2_rn(Y.x, Y.y);
    }
}

// ---- Kernel C: final (R11 shape). grid 128 = (j,b). Sum 8 fp16 half-rows
// via int4 loads, conjugate-mirror upper half, one inverse FFT, write Re/N.
__global__ __launch_bounds__(NT, 2) void ldr_fin_k(
    const __half2* __restrict__ Ph, float* __restrict__ out)
{
    __shared__ float2 lds[NFFT];
    __shared__ float2 sh[NFFT/2];      // summed half-spectrum (packed elem 0)
    const int tid = threadIdx.x;
    const int bid = blockIdx.x;        // j*BATCH + b
    const int b = bid & (BATCH - 1);
    const int j = bid >> 5;

    float2 a[8];
    #pragma unroll
    for (int k = 0; k < 8; ++k) a[k] = make_float2(0.f, 0.f);
    #pragma unroll
    for (int u = 0; u < 8; ++u) {
        const int4* row4 = (const int4*)(Ph + (size_t)((u*COUT + j)*BATCH + b) * (NFFT/2));
        #pragma unroll
        for (int c = 0; c < 2; ++c) {
            const int4 w = row4[tid + 256*c];
            const int ww[4] = { w.x, w.y, w.z, w.w };
            #pragma unroll
            for (int r = 0; r < 4; ++r) {
                __half2 h = *(const __half2*)&ww[r];
                float2 f = __half22float2(h);
                a[c*4+r] = cadd(a[c*4+r], f);
            }
        }
    }
    float4* sh4 = (float4*)sh;
    #pragma unroll
    for (int c = 0; c < 2; ++c) {
        sh4[2*(tid + 256*c) + 0] = make_float4(a[c*4+0].x, a[c*4+0].y, a[c*4+1].x, a[c*4+1].y);
        sh4[2*(tid + 256*c) + 1] = make_float4(a[c*4+2].x, a[c*4+2].y, a[c*4+3].x, a[c*4+3].y);
    }
    __syncthreads();

    const float dc  = sh[0].x;
    const float nyq = sh[0].y;
    float2 v[16];
    #pragma unroll
    for (int k = 0; k < 8; ++k) v[k] = sh[tid + 256*k];
    if (tid == 0) v[0] = make_float2(dc, 0.0f);
    #pragma unroll
    for (int k = 8; k < 16; ++k) {
        const int m = 4096 - (tid + 256*k);          // mirror index in [1,2048]
        if (m == 2048) {                              // only tid==0, k==8
            v[k] = make_float2(nyq, 0.0f);
        } else {
            float2 c = sh[m];
            v[k] = make_float2(c.x, -c.y);            // conj
        }
    }
    // no barrier needed: fft writes lds[], sh[] untouched
    fft4096_r16<1>(v, lds, tid);
    const float invn = 1.0f / (float)NFFT;
    float* orow = out + (size_t)bid * NFFT;
    #pragma unroll
    for (int k = 0; k < 16; ++k) orow[tid + 256*k] = v[k].x * invn;
}

extern "C" void kernel_launch(void* const* d_in, const int* in_sizes, int n_in,
                              void* d_out, int out_size, void* d_ws, size_t ws_size,
                              hipStream_t stream) {
    const float* x = (const float*)d_in[0];   // (CIN, B, N)
    const float* G = (const float*)d_in[1];   // (CIN, COUT, R, N)
    const float* H = (const float*)d_in[2];   // (CIN, COUT, R, N)
    float* out = (float*)d_out;               // (COUT, B, N)

    float2*  Hc = (float2*)d_ws;                    // 32 packed pair rows (1 MB)
    float2*  Gf = Hc + (size_t)32 * NFFT;           // 64 rows (2 MB)
    float2*  Xf = Gf + (size_t)64 * NFFT;           // 128 rows (4 MB)
    __half2* Ph = (__half2*)(Xf + (size_t)128 * NFFT); // 1024 half-rows x 2048 h2 (8 MB)

    ldr_pre_k<<<224, NT, 0, stream>>>(x, G, H, Hc, Gf, Xf);
    ldr_mid_k<<<CIN * COUT * RANK * BATCH / 2, NT, 0, stream>>>(Hc, Xf, Gf, Ph);
    ldr_fin_k<<<COUT * BATCH, NT, 0, stream>>>(Ph, out);
}

// Round 3
// 108.190 us; speedup vs baseline: 1.0327x; 1.0327x over previous
//
#include <hip/hip_runtime.h>
#include <hip/hip_fp16.h>
#include <math.h>

// LDR toep_corner via FFT chain, radix-16 registerized FFT (4096 = 16^3).
// out[j,b] = Re ifft( sum_{i,s} Gf_ijs . fft( D . fft( Hf_ijs . Xf_ib ) ) )
// Hf = fft(D.H), Xf = ifft(conj(D).x), Gf = fft(G), D_k = exp(i*pi*k/N).
//
// R16 == R15 resubmitted verbatim (R2 bench was an infra failure: container
// acquisition failed twice; kernel never ran).
// R15 = R13 (proven 90.5us) + two changes:
//  * ldr_mid_k -> __launch_bounds__(256,3): VGPR cap 168 (holds the ~90-reg
//    dft16 live set, NO spill — R14's (256,4) cap 128 forced VGPR=64 + 85MB
//    scratch, mid 144us), 12 waves/CU vs 8. LDS 3x32KB=96KB of 160KB fits.
//    pre(224)/fin(128) grids get <=1 block/CU anyway -> stay (256,2).
//  * D-twiddle chains (dstep^k serial cmul, depth 15) replaced by per-k
//    compile-time constants e^{i*pi*k/16} (R14-proven numerically, absmax
//    unchanged): removes a serial ~90cy dependency + ~90 VALU insts.
//  * R14's sched_barrier(0) fences removed (R13 scheduling restored).
// Fixed cost: ~44us harness fill of 256MB d_ws + restore, not controllable.

#define NFFT  4096
#define NT    256
#define CIN   4
#define COUT  4
#define RANK  4
#define BATCH 32
#define PI_F  3.14159265358979323846f

// cos/sin(pi*k/16), k=0..15 (compile-time folded in full-unrolled loops).
constexpr float CP16[16] = {
    1.0000000000000000f,  0.9807852804032304f,  0.9238795325112867f,  0.8314696123025452f,
    0.7071067811865476f,  0.5555702330196022f,  0.3826834323650898f,  0.1950903220161282f,
    0.0000000000000000f, -0.1950903220161282f, -0.3826834323650898f, -0.5555702330196022f,
   -0.7071067811865476f, -0.8314696123025452f, -0.9238795325112867f, -0.9807852804032304f };
constexpr float SP16[16] = {
    0.0000000000000000f,  0.1950903220161282f,  0.3826834323650898f,  0.5555702330196022f,
    0.7071067811865476f,  0.8314696123025452f,  0.9238795325112867f,  0.9807852804032304f,
    1.0000000000000000f,  0.9807852804032304f,  0.9238795325112867f,  0.8314696123025452f,
    0.7071067811865476f,  0.5555702330196022f,  0.3826834323650898f,  0.1950903220161282f };

__device__ __forceinline__ float2 cmul(float2 a, float2 b) {
    return make_float2(a.x*b.x - a.y*b.y, a.x*b.y + a.y*b.x);
}
__device__ __forceinline__ float2 cadd(float2 a, float2 b){ return make_float2(a.x+b.x, a.y+b.y); }
__device__ __forceinline__ float2 csub(float2 a, float2 b){ return make_float2(a.x-b.x, a.y-b.y); }

// LDS bank swizzle (R2-proven: SQ_LDS_BANK_CONFLICT ~ 0).
__device__ __forceinline__ int SW(int e){ return e ^ ((e >> 4) & 15); }

// 16-point DFT in registers, natural order in/out (R2-proven numerics).
template<int SIGN>
__device__ __forceinline__ void dft16(float2 v[16]) {
    const float sgn = (float)SIGN;
    const float C8 = 0.923879532511287f, S8 = 0.382683432365090f, H2 = 0.707106781186548f;
    const float2 w1 = make_float2( C8,  sgn*S8);
    const float2 w2 = make_float2( H2,  sgn*H2);
    const float2 w3 = make_float2( S8,  sgn*C8);
    const float2 w4 = make_float2(0.f,  sgn);
    const float2 w6 = make_float2(-H2,  sgn*H2);
    const float2 w9 = make_float2(-C8, -sgn*S8);
    float2 t[16];
    #pragma unroll
    for (int p = 0; p < 4; ++p) {
        float2 a0 = v[p], a1 = v[p+4], a2 = v[p+8], a3 = v[p+12];
        float2 b0 = cadd(a0,a2), b1 = csub(a0,a2), b2 = cadd(a1,a3), b3 = csub(a1,a3);
        float2 ib3 = make_float2(-sgn*b3.y, sgn*b3.x);   // SIGN*i*b3
        float2 X0 = cadd(b0,b2), X2c = csub(b0,b2);
        float2 X1 = cadd(b1,ib3), X3 = csub(b1,ib3);
        if (p == 1) { X1 = cmul(X1,w1); X2c = cmul(X2c,w2); X3 = cmul(X3,w3); }
        else if (p == 2) { X1 = cmul(X1,w2); X2c = cmul(X2c,w4); X3 = cmul(X3,w6); }
        else if (p == 3) { X1 = cmul(X1,w3); X2c = cmul(X2c,w6); X3 = cmul(X3,w9); }
        t[4*p+0]=X0; t[4*p+1]=X1; t[4*p+2]=X2c; t[4*p+3]=X3;
    }
    #pragma unroll
    for (int q = 0; q < 4; ++q) {
        float2 a0 = t[q], a1 = t[q+4], a2 = t[q+8], a3 = t[q+12];
        float2 b0 = cadd(a0,a2), b1 = csub(a0,a2), b2 = cadd(a1,a3), b3 = csub(a1,a3);
        float2 ib3 = make_float2(-sgn*b3.y, sgn*b3.x);
        v[q+0]  = cadd(b0,b2);
        v[q+8]  = csub(b0,b2);
        v[q+4]  = cadd(b1,ib3);
        v[q+12] = csub(b1,ib3);
    }
}

// v[k] *= e^{i*k*ang}; two independent power chains (depth ~8 not 15).
__device__ __forceinline__ void twiddle16(float2 v[16], float ang) {
    float sn, cs; __sincosf(ang, &sn, &cs);
    float2 w  = make_float2(cs, sn);
    float2 w2 = cmul(w, w);
    float2 to = w;   // odd powers
    float2 te = w2;  // even powers
    v[1] = cmul(v[1], to);
    v[2] = cmul(v[2], te);
    #pragma unroll
    for (int k = 3; k < 16; k += 2) {
        to = cmul(to, w2); v[k] = cmul(v[k], to);
        if (k + 1 < 16) { te = cmul(te, w2); v[k+1] = cmul(v[k+1], te); }
    }
}

// Stockham radix-16, 3 stages, single 32KB buffer (R2-proven).
// Input: v[r] = x[tid + 256r]. Output: v[k] = X[tid + 256k].
// Trailing barrier: lds reusable by caller on exit.
template<int SIGN>
__device__ void fft4096_r16(float2 v[16], float2* lds, int tid) {
    dft16<SIGN>(v);
    twiddle16(v, (float)SIGN * 2.0f * PI_F * (float)tid / 4096.0f);
    #pragma unroll
    for (int k = 0; k < 16; ++k) lds[SW(16*tid + k)] = v[k];
    __syncthreads();
    #pragma unroll
    for (int r = 0; r < 16; ++r) v[r] = lds[SW(tid + 256*r)];
    dft16<SIGN>(v);
    twiddle16(v, (float)SIGN * 2.0f * PI_F * (float)(tid >> 4) / 256.0f);
    __syncthreads();                       // in-place: all reads before any write
    {
        const int q = tid & 15, p = tid >> 4;
        #pragma unroll
        for (int k = 0; k < 16; ++k) lds[SW(q + 256*p + 16*k)] = v[k];
    }
    __syncthreads();
    #pragma unroll
    for (int r = 0; r < 16; ++r) v[r] = lds[SW(tid + 256*r)];
    dft16<SIGN>(v);
    __syncthreads();                       // lds reusable by caller
}

// ---- Kernel A: precompute. grid 224 x 256.
// bid 0..31: Hc pair rows (ONE fft of D.(h0 + i*h1), no unpack needed);
// bid 32..95: Gf rows; bid 96..223: Xf rows.
__global__ __launch_bounds__(NT, 2) void ldr_pre_k(
    const float* __restrict__ x, const float* __restrict__ G, const float* __restrict__ H,
    float2* __restrict__ Hc, float2* __restrict__ Gf, float2* __restrict__ Xf)
{
    __shared__ float2 lds[NFFT];
    const int tid = threadIdx.x;
    const int bid = blockIdx.x;
    float2 v[16];
    if (bid < 32) {
        // Hc[p] = fft(D.(H[2p] + i*H[2p+1])) = Hf[2p] + i*Hf[2p+1]
        const float* h0 = H + (size_t)(2*bid)     * NFFT;
        const float* h1 = H + (size_t)(2*bid + 1) * NFFT;
        float sn, cs; __sincosf(PI_F * (float)tid / (float)NFFT, &sn, &cs);
        const float2 dt = make_float2(cs, sn);
        #pragma unroll
        for (int k = 0; k < 16; ++k) {
            const int e = tid + 256*k;
            const float2 d = cmul(dt, make_float2(CP16[k], SP16[k]));  // e^{i*pi*e/N}
            v[k] = cmul(d, make_float2(h0[e], h1[e]));
        }
        fft4096_r16<-1>(v, lds, tid);
        float2* o = Hc + (size_t)bid * NFFT;
        #pragma unroll
        for (int k = 0; k < 16; ++k) o[tid + 256*k] = v[k];
    } else if (bid < 96) {
        const int row = bid - 32;
        const float* g = G + (size_t)row * NFFT;
        #pragma unroll
        for (int k = 0; k < 16; ++k) v[k] = make_float2(g[tid + 256*k], 0.0f);
        fft4096_r16<-1>(v, lds, tid);
        float2* o = Gf + (size_t)row * NFFT;
        #pragma unroll
        for (int k = 0; k < 16; ++k) o[tid + 256*k] = v[k];
    } else {
        const int row = bid - 96;
        const float* xp = x + (size_t)row * NFFT;
        float sn, cs; __sincosf(PI_F * (float)tid / (float)NFFT, &sn, &cs);
        const float2 dt = make_float2(cs, -sn);                        // conj(D) thread part
        #pragma unroll
        for (int k = 0; k < 16; ++k) {
            const int e = tid + 256*k;
            const float2 d = cmul(dt, make_float2(CP16[k], -SP16[k])); // e^{-i*pi*e/N}
            float xv = xp[e];
            v[k] = make_float2(d.x*xv, d.y*xv);
        }
        fft4096_r16<1>(v, lds, tid);
        const float invn = 1.0f / (float)NFFT;
        float2* o = Xf + (size_t)row * NFFT;
        #pragma unroll
        for (int k = 0; k < 16; ++k) o[tid + 256*k] = make_float2(v[k].x*invn, v[k].y*invn);
    }
}

// ---- Kernel B: middle. grid 1024 = (ij*2 + pr)(32) x b(32); one rank PAIR
// per wg. Input P = Hc[ip].Xf (one cmul/elem — Hc is the packed pair). Two
// full FFTs, no regs live across FFT calls (spill-free shape, R7-proven).
// R15: (256,3) -> VGPR cap 168 (no spill), 12 waves/CU, LDS 96KB/160KB.
// Hermitian unpack of Z = fft(t0)+i*fft(t1) via mirror staged in LDS.
// Lower-half Y as fp16, DC.x / Nyq.x packed into element 0; plane u = i*2+pr
// (8 planes), row ((u*COUT + j)*BATCH + b), 2048 half2.
__global__ __launch_bounds__(NT, 3) void ldr_mid_k(
    const float2* __restrict__ Hc, const float2* __restrict__ Xf,
    const float2* __restrict__ Gf, __half2* __restrict__ Ph)
{
    __shared__ float2 lds[NFFT];
    const int tid = threadIdx.x;
    const int bid = blockIdx.x;
    const int b   = bid & (BATCH - 1);
    const int ip  = bid >> 5;           // ij*2 + pr, [0,32)
    const int pr  = ip & 1;
    const int ij  = ip >> 1;
    const int i   = ij >> 2;            // COUT = 4
    const int j   = ij & 3;
    const int r0  = ij*RANK + 2*pr;     // G rows s0 = r0, s1 = r0+1
    const float2* xrow = Xf + (size_t)(i*BATCH + b) * NFFT;
    const float2* hc = Hc + (size_t)ip * NFFT;
    const float2* g0 = Gf + (size_t)r0 * NFFT;
    const float2* g1 = g0 + NFFT;

    float2 v[16];
    #pragma unroll
    for (int k = 0; k < 16; ++k) {
        const int e = tid + 256*k;
        v[k] = cmul(hc[e], xrow[e]);    // = (h0+i*h1).x = h0.x + i*(h1.x)
    }
    fft4096_r16<-1>(v, lds, tid);
    {
        // D_e = e^{i*pi*(tid+256k)/4096} = e^{i*pi*tid/4096} * e^{i*pi*k/16}
        float sn, cs; __sincosf(PI_F * (float)tid / (float)NFFT, &sn, &cs);
        const float2 dt = make_float2(cs, sn);
        #pragma unroll
        for (int k = 0; k < 16; ++k) {
            const float2 d = cmul(dt, make_float2(CP16[k], SP16[k]));
            v[k] = cmul(v[k], d);
        }
    }
    fft4096_r16<-1>(v, lds, tid);       // Z = fft(t0) + i*fft(t1); lds free after

    // Stage upper half of Z for mirror access.
    #pragma unroll
    for (int k = 8; k < 16; ++k) lds[SW(tid + 256*k)] = v[k];
    __syncthreads();

    const int u = i*2 + pr;             // plane in [0,8)
    __half2* prow = Ph + (size_t)((u*COUT + j)*BATCH + b) * (NFFT/2);
    #pragma unroll
    for (int k = 0; k < 8; ++k) {
        const int e = tid + 256*k;
        const float2 Zk = v[k];
        float2 Zm;
        if (e == 0) Zm = Zk;
        else        Zm = lds[SW(4096 - e)];
        const float2 V1 = make_float2(0.5f*(Zk.x + Zm.x), 0.5f*(Zk.y - Zm.y));
        const float2 V2 = make_float2(0.5f*(Zk.y + Zm.y), 0.5f*(Zm.x - Zk.x));
        float2 Y = cadd(cmul(g0[e], V1), cmul(g1[e], V2));
        if (k == 0 && tid == 0) {
            const float2 Zn = v[8];
            const float Ynyq = g0[2048].x * Zn.x + g1[2048].x * Zn.y;
            Y = make_float2(Y.x, Ynyq);      // pack DC.x / Nyq.x
        }
        prow[e] = __floats2half2_rn(Y.x, Y.y);
    }
}

// ---- Kernel C: final (R11 shape). grid 128 = (j,b). Sum 8 fp16 half-rows
// via int4 loads, conjugate-mirror upper half, one inverse FFT, write Re/N.
__global__ __launch_bounds__(NT, 2) void ldr_fin_k(
    const __half2* __restrict__ Ph, float* __restrict__ out)
{
    __shared__ float2 lds[NFFT];
    __shared__ float2 sh[NFFT/2];      // summed half-spectrum (packed elem 0)
    const int tid = threadIdx.x;
    const int bid = blockIdx.x;        // j*BATCH + b
    const int b = bid & (BATCH - 1);
    const int j = bid >> 5;

    float2 a[8];
    #pragma unroll
    for (int k = 0; k < 8; ++k) a[k] = make_float2(0.f, 0.f);
    #pragma unroll
    for (int u = 0; u < 8; ++u) {
        const int4* row4 = (const int4*)(Ph + (size_t)((u*COUT + j)*BATCH + b) * (NFFT/2));
        #pragma unroll
        for (int c = 0; c < 2; ++c) {
            const int4 w = row4[tid + 256*c];
            const int ww[4] = { w.x, w.y, w.z, w.w };
            #pragma unroll
            for (int r = 0; r < 4; ++r) {
                __half2 h = *(const __half2*)&ww[r];
                float2 f = __half22float2(h);
                a[c*4+r] = cadd(a[c*4+r], f);
            }
        }
    }
    float4* sh4 = (float4*)sh;
    #pragma unroll
    for (int c = 0; c < 2; ++c) {
        sh4[2*(tid + 256*c) + 0] = make_float4(a[c*4+0].x, a[c*4+0].y, a[c*4+1].x, a[c*4+1].y);
        sh4[2*(tid + 256*c) + 1] = make_float4(a[c*4+2].x, a[c*4+2].y, a[c*4+3].x, a[c*4+3].y);
    }
    __syncthreads();

    const float dc  = sh[0].x;
    const float nyq = sh[0].y;
    float2 v[16];
    #pragma unroll
    for (int k = 0; k < 8; ++k) v[k] = sh[tid + 256*k];
    if (tid == 0) v[0] = make_float2(dc, 0.0f);
    #pragma unroll
    for (int k = 8; k < 16; ++k) {
        const int m = 4096 - (tid + 256*k);          // mirror index in [1,2048]
        if (m == 2048) {                              // only tid==0, k==8
            v[k] = make_float2(nyq, 0.0f);
        } else {
            float2 c = sh[m];
            v[k] = make_float2(c.x, -c.y);            // conj
        }
    }
    // no barrier needed: fft writes lds[], sh[] untouched
    fft4096_r16<1>(v, lds, tid);
    const float invn = 1.0f / (float)NFFT;
    float* orow = out + (size_t)bid * NFFT;
    #pragma unroll
    for (int k = 0; k < 16; ++k) orow[tid + 256*k] = v[k].x * invn;
}

extern "C" void kernel_launch(void* const* d_in, const int* in_sizes, int n_in,
                              void* d_out, int out_size, void* d_ws, size_t ws_size,
                              hipStream_t stream) {
    const float* x = (const float*)d_in[0];   // (CIN, B, N)
    const float* G = (const float*)d_in[1];   // (CIN, COUT, R, N)
    const float* H = (const float*)d_in[2];   // (CIN, COUT, R, N)
    float* out = (float*)d_out;               // (COUT, B, N)

    float2*  Hc = (float2*)d_ws;                    // 32 packed pair rows (1 MB)
    float2*  Gf = Hc + (size_t)32 * NFFT;           // 64 rows (2 MB)
    float2*  Xf = Gf + (size_t)64 * NFFT;           // 128 rows (4 MB)
    __half2* Ph = (__half2*)(Xf + (size_t)128 * NFFT); // 1024 half-rows x 2048 h2 (8 MB)

    ldr_pre_k<<<224, NT, 0, stream>>>(x, G, H, Hc, Gf, Xf);
    ldr_mid_k<<<CIN * COUT * RANK * BATCH / 2, NT, 0, stream>>>(Hc, Xf, Gf, Ph);
    ldr_fin_k<<<COUT * BATCH, NT, 0, stream>>>(Ph, out);
}

// Round 4
// 102.064 us; speedup vs baseline: 1.0947x; 1.0600x over previous
//
#include <hip/hip_runtime.h>
#include <hip/hip_fp16.h>
#include <math.h>

// LDR toep_corner via FFT chain, radix-16 registerized FFT (4096 = 16^3).
// out[j,b] = Re ifft( sum_{i,s} Gf_ijs . fft( D . fft( Hf_ijs . Xf_ib ) ) )
// Hf = fft(D.H), Xf = ifft(conj(D).x), Gf = fft(G), D_k = exp(i*pi*k/N).
//
// R17 = R13 (proven 90.5us) + CP16 twiddle rider (R14/R15-proven numerics)
//       + mid 2-products-per-block:
//  * ldr_mid_k grid 1024 -> 512: each block keeps ip fixed and processes
//    b = 2*bp and 2*bp+1 sequentially. hc + g0/g1 are re-read from the
//    block's own XCD L2 on product 2 (was: different block, L3/HBM).
//    Traffic 106MB -> ~74MB; single resident round (512 = 2 blocks/CU x
//    256 CU); half the block preambles. Product body is instruction-
//    identical to R13 -> bit-exact, absmax must stay 0.03125.
//  * Product loop is '#pragma unroll 1' ON PURPOSE: rolling prevents
//    cross-product load hoisting (keeps R13's proven register pressure).
//  * launch_bounds stays (256,2) EVERYWHERE: R14 (cap 128) collapsed the
//    allocator (VGPR=64, 85MB scratch, mid 144us); R15 (cap 170) still
//    regressed ~10us. Mid's natural demand >170 -> never cap below it.
// Fixed cost: ~44us harness fill of 256MB d_ws + restore, not controllable.

#define NFFT  4096
#define NT    256
#define CIN   4
#define COUT  4
#define RANK  4
#define BATCH 32
#define PI_F  3.14159265358979323846f

// cos/sin(pi*k/16), k=0..15 (compile-time folded in full-unrolled loops).
constexpr float CP16[16] = {
    1.0000000000000000f,  0.9807852804032304f,  0.9238795325112867f,  0.8314696123025452f,
    0.7071067811865476f,  0.5555702330196022f,  0.3826834323650898f,  0.1950903220161282f,
    0.0000000000000000f, -0.1950903220161282f, -0.3826834323650898f, -0.5555702330196022f,
   -0.7071067811865476f, -0.8314696123025452f, -0.9238795325112867f, -0.9807852804032304f };
constexpr float SP16[16] = {
    0.0000000000000000f,  0.1950903220161282f,  0.3826834323650898f,  0.5555702330196022f,
    0.7071067811865476f,  0.8314696123025452f,  0.9238795325112867f,  0.9807852804032304f,
    1.0000000000000000f,  0.9807852804032304f,  0.9238795325112867f,  0.8314696123025452f,
    0.7071067811865476f,  0.5555702330196022f,  0.3826834323650898f,  0.1950903220161282f };

__device__ __forceinline__ float2 cmul(float2 a, float2 b) {
    return make_float2(a.x*b.x - a.y*b.y, a.x*b.y + a.y*b.x);
}
__device__ __forceinline__ float2 cadd(float2 a, float2 b){ return make_float2(a.x+b.x, a.y+b.y); }
__device__ __forceinline__ float2 csub(float2 a, float2 b){ return make_float2(a.x-b.x, a.y-b.y); }

// LDS bank swizzle (R2-proven: SQ_LDS_BANK_CONFLICT ~ 0).
__device__ __forceinline__ int SW(int e){ return e ^ ((e >> 4) & 15); }

// 16-point DFT in registers, natural order in/out (R2-proven numerics).
template<int SIGN>
__device__ __forceinline__ void dft16(float2 v[16]) {
    const float sgn = (float)SIGN;
    const float C8 = 0.923879532511287f, S8 = 0.382683432365090f, H2 = 0.707106781186548f;
    const float2 w1 = make_float2( C8,  sgn*S8);
    const float2 w2 = make_float2( H2,  sgn*H2);
    const float2 w3 = make_float2( S8,  sgn*C8);
    const float2 w4 = make_float2(0.f,  sgn);
    const float2 w6 = make_float2(-H2,  sgn*H2);
    const float2 w9 = make_float2(-C8, -sgn*S8);
    float2 t[16];
    #pragma unroll
    for (int p = 0; p < 4; ++p) {
        float2 a0 = v[p], a1 = v[p+4], a2 = v[p+8], a3 = v[p+12];
        float2 b0 = cadd(a0,a2), b1 = csub(a0,a2), b2 = cadd(a1,a3), b3 = csub(a1,a3);
        float2 ib3 = make_float2(-sgn*b3.y, sgn*b3.x);   // SIGN*i*b3
        float2 X0 = cadd(b0,b2), X2c = csub(b0,b2);
        float2 X1 = cadd(b1,ib3), X3 = csub(b1,ib3);
        if (p == 1) { X1 = cmul(X1,w1); X2c = cmul(X2c,w2); X3 = cmul(X3,w3); }
        else if (p == 2) { X1 = cmul(X1,w2); X2c = cmul(X2c,w4); X3 = cmul(X3,w6); }
        else if (p == 3) { X1 = cmul(X1,w3); X2c = cmul(X2c,w6); X3 = cmul(X3,w9); }
        t[4*p+0]=X0; t[4*p+1]=X1; t[4*p+2]=X2c; t[4*p+3]=X3;
    }
    #pragma unroll
    for (int q = 0; q < 4; ++q) {
        float2 a0 = t[q], a1 = t[q+4], a2 = t[q+8], a3 = t[q+12];
        float2 b0 = cadd(a0,a2), b1 = csub(a0,a2), b2 = cadd(a1,a3), b3 = csub(a1,a3);
        float2 ib3 = make_float2(-sgn*b3.y, sgn*b3.x);
        v[q+0]  = cadd(b0,b2);
        v[q+8]  = csub(b0,b2);
        v[q+4]  = cadd(b1,ib3);
        v[q+12] = csub(b1,ib3);
    }
}

// v[k] *= e^{i*k*ang}; two independent power chains (depth ~8 not 15).
__device__ __forceinline__ void twiddle16(float2 v[16], float ang) {
    float sn, cs; __sincosf(ang, &sn, &cs);
    float2 w  = make_float2(cs, sn);
    float2 w2 = cmul(w, w);
    float2 to = w;   // odd powers
    float2 te = w2;  // even powers
    v[1] = cmul(v[1], to);
    v[2] = cmul(v[2], te);
    #pragma unroll
    for (int k = 3; k < 16; k += 2) {
        to = cmul(to, w2); v[k] = cmul(v[k], to);
        if (k + 1 < 16) { te = cmul(te, w2); v[k+1] = cmul(v[k+1], te); }
    }
}

// Stockham radix-16, 3 stages, single 32KB buffer (R2-proven).
// Input: v[r] = x[tid + 256r]. Output: v[k] = X[tid + 256k].
// Trailing barrier: lds reusable by caller on exit.
template<int SIGN>
__device__ void fft4096_r16(float2 v[16], float2* lds, int tid) {
    dft16<SIGN>(v);
    twiddle16(v, (float)SIGN * 2.0f * PI_F * (float)tid / 4096.0f);
    #pragma unroll
    for (int k = 0; k < 16; ++k) lds[SW(16*tid + k)] = v[k];
    __syncthreads();
    #pragma unroll
    for (int r = 0; r < 16; ++r) v[r] = lds[SW(tid + 256*r)];
    dft16<SIGN>(v);
    twiddle16(v, (float)SIGN * 2.0f * PI_F * (float)(tid >> 4) / 256.0f);
    __syncthreads();                       // in-place: all reads before any write
    {
        const int q = tid & 15, p = tid >> 4;
        #pragma unroll
        for (int k = 0; k < 16; ++k) lds[SW(q + 256*p + 16*k)] = v[k];
    }
    __syncthreads();
    #pragma unroll
    for (int r = 0; r < 16; ++r) v[r] = lds[SW(tid + 256*r)];
    dft16<SIGN>(v);
    __syncthreads();                       // lds reusable by caller
}

// ---- Kernel A: precompute. grid 224 x 256.
// bid 0..31: Hc pair rows (ONE fft of D.(h0 + i*h1), no unpack needed);
// bid 32..95: Gf rows; bid 96..223: Xf rows.
__global__ __launch_bounds__(NT, 2) void ldr_pre_k(
    const float* __restrict__ x, const float* __restrict__ G, const float* __restrict__ H,
    float2* __restrict__ Hc, float2* __restrict__ Gf, float2* __restrict__ Xf)
{
    __shared__ float2 lds[NFFT];
    const int tid = threadIdx.x;
    const int bid = blockIdx.x;
    float2 v[16];
    if (bid < 32) {
        // Hc[p] = fft(D.(H[2p] + i*H[2p+1])) = Hf[2p] + i*Hf[2p+1]
        const float* h0 = H + (size_t)(2*bid)     * NFFT;
        const float* h1 = H + (size_t)(2*bid + 1) * NFFT;
        float sn, cs; __sincosf(PI_F * (float)tid / (float)NFFT, &sn, &cs);
        const float2 dt = make_float2(cs, sn);
        #pragma unroll
        for (int k = 0; k < 16; ++k) {
            const int e = tid + 256*k;
            const float2 d = cmul(dt, make_float2(CP16[k], SP16[k]));  // e^{i*pi*e/N}
            v[k] = cmul(d, make_float2(h0[e], h1[e]));
        }
        fft4096_r16<-1>(v, lds, tid);
        float2* o = Hc + (size_t)bid * NFFT;
        #pragma unroll
        for (int k = 0; k < 16; ++k) o[tid + 256*k] = v[k];
    } else if (bid < 96) {
        const int row = bid - 32;
        const float* g = G + (size_t)row * NFFT;
        #pragma unroll
        for (int k = 0; k < 16; ++k) v[k] = make_float2(g[tid + 256*k], 0.0f);
        fft4096_r16<-1>(v, lds, tid);
        float2* o = Gf + (size_t)row * NFFT;
        #pragma unroll
        for (int k = 0; k < 16; ++k) o[tid + 256*k] = v[k];
    } else {
        const int row = bid - 96;
        const float* xp = x + (size_t)row * NFFT;
        float sn, cs; __sincosf(PI_F * (float)tid / (float)NFFT, &sn, &cs);
        const float2 dt = make_float2(cs, -sn);                        // conj(D) thread part
        #pragma unroll
        for (int k = 0; k < 16; ++k) {
            const int e = tid + 256*k;
            const float2 d = cmul(dt, make_float2(CP16[k], -SP16[k])); // e^{-i*pi*e/N}
            float xv = xp[e];
            v[k] = make_float2(d.x*xv, d.y*xv);
        }
        fft4096_r16<1>(v, lds, tid);
        const float invn = 1.0f / (float)NFFT;
        float2* o = Xf + (size_t)row * NFFT;
        #pragma unroll
        for (int k = 0; k < 16; ++k) o[tid + 256*k] = make_float2(v[k].x*invn, v[k].y*invn);
    }
}

// ---- Kernel B: middle. grid 512 = ip(32) x bpair(16); one rank PAIR and
// TWO batch values per wg (b = 2*bp, 2*bp+1). hc/g0/g1 shared across the
// two products -> product 2's reads hit own-XCD L2. Per-product body is
// R13's exact instruction sequence (bit-exact numerics).
// Input P = Hc[ip].Xf (one cmul/elem — Hc is the packed pair). Two full
// FFTs, no regs live across FFT calls (spill-free shape, R7-proven).
// Hermitian unpack of Z = fft(t0)+i*fft(t1) via mirror staged in LDS.
// Lower-half Y as fp16, DC.x / Nyq.x packed into element 0; plane u = i*2+pr
// (8 planes), row ((u*COUT + j)*BATCH + b), 2048 half2.
__global__ __launch_bounds__(NT, 2) void ldr_mid_k(
    const float2* __restrict__ Hc, const float2* __restrict__ Xf,
    const float2* __restrict__ Gf, __half2* __restrict__ Ph)
{
    __shared__ float2 lds[NFFT];
    const int tid = threadIdx.x;
    const int bid = blockIdx.x;         // [0,512)
    const int bp  = bid & 15;           // batch pair index -> b = 2bp, 2bp+1
    const int ip  = bid >> 4;           // ij*2 + pr, [0,32)
    const int pr  = ip & 1;
    const int ij  = ip >> 1;
    const int i   = ij >> 2;            // COUT = 4
    const int j   = ij & 3;
    const int r0  = ij*RANK + 2*pr;     // G rows s0 = r0, s1 = r0+1
    const float2* hc = Hc + (size_t)ip * NFFT;
    const float2* g0 = Gf + (size_t)r0 * NFFT;
    const float2* g1 = g0 + NFFT;
    const int u = i*2 + pr;             // plane in [0,8)

    #pragma unroll 1                    // rolled: no cross-product hoisting
    for (int t = 0; t < 2; ++t) {
        const int b = 2*bp + t;
        const float2* xrow = Xf + (size_t)(i*BATCH + b) * NFFT;

        float2 v[16];
        #pragma unroll
        for (int k = 0; k < 16; ++k) {
            const int e = tid + 256*k;
            v[k] = cmul(hc[e], xrow[e]);    // = (h0+i*h1).x = h0.x + i*(h1.x)
        }
        fft4096_r16<-1>(v, lds, tid);
        {
            // D_e = e^{i*pi*(tid+256k)/4096} = e^{i*pi*tid/4096} * e^{i*pi*k/16}
            float sn, cs; __sincosf(PI_F * (float)tid / (float)NFFT, &sn, &cs);
            const float2 dt = make_float2(cs, sn);
            #pragma unroll
            for (int k = 0; k < 16; ++k) {
                const float2 d = cmul(dt, make_float2(CP16[k], SP16[k]));
                v[k] = cmul(v[k], d);
            }
        }
        fft4096_r16<-1>(v, lds, tid);   // Z = fft(t0) + i*fft(t1); lds free after

        // Stage upper half of Z for mirror access.
        #pragma unroll
        for (int k = 8; k < 16; ++k) lds[SW(tid + 256*k)] = v[k];
        __syncthreads();

        __half2* prow = Ph + (size_t)((u*COUT + j)*BATCH + b) * (NFFT/2);
        #pragma unroll
        for (int k = 0; k < 8; ++k) {
            const int e = tid + 256*k;
            const float2 Zk = v[k];
            float2 Zm;
            if (e == 0) Zm = Zk;
            else        Zm = lds[SW(4096 - e)];
            const float2 V1 = make_float2(0.5f*(Zk.x + Zm.x), 0.5f*(Zk.y - Zm.y));
            const float2 V2 = make_float2(0.5f*(Zk.y + Zm.y), 0.5f*(Zm.x - Zk.x));
            float2 Y = cadd(cmul(g0[e], V1), cmul(g1[e], V2));
            if (k == 0 && tid == 0) {
                const float2 Zn = v[8];
                const float Ynyq = g0[2048].x * Zn.x + g1[2048].x * Zn.y;
                Y = make_float2(Y.x, Ynyq);      // pack DC.x / Nyq.x
            }
            prow[e] = __floats2half2_rn(Y.x, Y.y);
        }
        __syncthreads();                // lds mirror reads done before next product's fft writes
    }
}

// ---- Kernel C: final (R11 shape). grid 128 = (j,b). Sum 8 fp16 half-rows
// via int4 loads, conjugate-mirror upper half, one inverse FFT, write Re/N.
__global__ __launch_bounds__(NT, 2) void ldr_fin_k(
    const __half2* __restrict__ Ph, float* __restrict__ out)
{
    __shared__ float2 lds[NFFT];
    __shared__ float2 sh[NFFT/2];      // summed half-spectrum (packed elem 0)
    const int tid = threadIdx.x;
    const int bid = blockIdx.x;        // j*BATCH + b
    const int b = bid & (BATCH - 1);
    const int j = bid >> 5;

    float2 a[8];
    #pragma unroll
    for (int k = 0; k < 8; ++k) a[k] = make_float2(0.f, 0.f);
    #pragma unroll
    for (int u = 0; u < 8; ++u) {
        const int4* row4 = (const int4*)(Ph + (size_t)((u*COUT + j)*BATCH + b) * (NFFT/2));
        #pragma unroll
        for (int c = 0; c < 2; ++c) {
            const int4 w = row4[tid + 256*c];
            const int ww[4] = { w.x, w.y, w.z, w.w };
            #pragma unroll
            for (int r = 0; r < 4; ++r) {
                __half2 h = *(const __half2*)&ww[r];
                float2 f = __half22float2(h);
                a[c*4+r] = cadd(a[c*4+r], f);
            }
        }
    }
    float4* sh4 = (float4*)sh;
    #pragma unroll
    for (int c = 0; c < 2; ++c) {
        sh4[2*(tid + 256*c) + 0] = make_float4(a[c*4+0].x, a[c*4+0].y, a[c*4+1].x, a[c*4+1].y);
        sh4[2*(tid + 256*c) + 1] = make_float4(a[c*4+2].x, a[c*4+2].y, a[c*4+3].x, a[c*4+3].y);
    }
    __syncthreads();

    const float dc  = sh[0].x;
    const float nyq = sh[0].y;
    float2 v[16];
    #pragma unroll
    for (int k = 0; k < 8; ++k) v[k] = sh[tid + 256*k];
    if (tid == 0) v[0] = make_float2(dc, 0.0f);
    #pragma unroll
    for (int k = 8; k < 16; ++k) {
        const int m = 4096 - (tid + 256*k);          // mirror index in [1,2048]
        if (m == 2048) {                              // only tid==0, k==8
            v[k] = make_float2(nyq, 0.0f);
        } else {
            float2 c = sh[m];
            v[k] = make_float2(c.x, -c.y);            // conj
        }
    }
    // no barrier needed: fft writes lds[], sh[] untouched
    fft4096_r16<1>(v, lds, tid);
    const float invn = 1.0f / (float)NFFT;
    float* orow = out + (size_t)bid * NFFT;
    #pragma unroll
    for (int k = 0; k < 16; ++k) orow[tid + 256*k] = v[k].x * invn;
}

extern "C" void kernel_launch(void* const* d_in, const int* in_sizes, int n_in,
                              void* d_out, int out_size, void* d_ws, size_t ws_size,
                              hipStream_t stream) {
    const float* x = (const float*)d_in[0];   // (CIN, B, N)
    const float* G = (const float*)d_in[1];   // (CIN, COUT, R, N)
    const float* H = (const float*)d_in[2];   // (CIN, COUT, R, N)
    float* out = (float*)d_out;               // (COUT, B, N)

    float2*  Hc = (float2*)d_ws;                    // 32 packed pair rows (1 MB)
    float2*  Gf = Hc + (size_t)32 * NFFT;           // 64 rows (2 MB)
    float2*  Xf = Gf + (size_t)64 * NFFT;           // 128 rows (4 MB)
    __half2* Ph = (__half2*)(Xf + (size_t)128 * NFFT); // 1024 half-rows x 2048 h2 (8 MB)

    ldr_pre_k<<<224, NT, 0, stream>>>(x, G, H, Hc, Gf, Xf);
    ldr_mid_k<<<512, NT, 0, stream>>>(Hc, Xf, Gf, Ph);   // 512 = ip(32) x bpair(16)
    ldr_fin_k<<<COUT * BATCH, NT, 0, stream>>>(Ph, out);
}

// Round 5
// 93.856 us; speedup vs baseline: 1.1905x; 1.0875x over previous
//
#include <hip/hip_runtime.h>
#include <hip/hip_fp16.h>
#include <math.h>

// LDR toep_corner via FFT chain, radix-16 registerized FFT (4096 = 16^3).
// out[j,b] = Re ifft( sum_{i,s} Gf_ijs . fft( D . fft( Hf_ijs . Xf_ib ) ) )
// Hf = fft(D.H), Xf = ifft(conj(D).x), Gf = fft(G), D_k = exp(i*pi*k/N).
//
// R18 = R13 (proven 90.5us) + CP16 twiddle rider + mid PAIRED-ILP rewrite:
//  * ldr_mid_k grid 512 = ip(32) x bpair(16); each block computes b=2bp and
//    2bp+1 SIMULTANEOUSLY: v0[16]+v1[16] in registers through a paired FFT
//    (two LDS buffers, shared barriers). Per product: barriers HALVED,
//    hc/g0/g1 loaded ONCE for both (register reuse), one shared D-twiddle +
//    twiddle16 sincos chain. Two independent dep chains/thread = ILP where
//    TLP is capped at 2 waves/SIMD.
//  * R17's '#pragma unroll 1' product loop is GONE (it made the allocator
//    target the 128-VGPR boundary and spill ~220B/thread: VGPR=128,
//    WRITE_SIZE 36.9MB vs 8MB ideal, mid 49us). Straight-line paired code,
//    peak live ~150 VGPR, fits (256,2)'s 256 cap naturally.
//  * Per-product arithmetic is value-identical to R13 -> absmax 0.03125.
//  * LDS 2x32KB=64KB/block -> still 2 blocks/CU (128KB of 160KB).
//  * launch_bounds (256,2) EVERYWHERE: caps below natural demand spill
//    (R14: cap128 -> VGPR64+85MB scratch; R15: cap170 -> ~+10us).
// Fixed cost: ~44us harness fill of 256MB d_ws + restore, not controllable.

#define NFFT  4096
#define NT    256
#define CIN   4
#define COUT  4
#define RANK  4
#define BATCH 32
#define PI_F  3.14159265358979323846f

// cos/sin(pi*k/16), k=0..15 (compile-time folded in full-unrolled loops).
constexpr float CP16[16] = {
    1.0000000000000000f,  0.9807852804032304f,  0.9238795325112867f,  0.8314696123025452f,
    0.7071067811865476f,  0.5555702330196022f,  0.3826834323650898f,  0.1950903220161282f,
    0.0000000000000000f, -0.1950903220161282f, -0.3826834323650898f, -0.5555702330196022f,
   -0.7071067811865476f, -0.8314696123025452f, -0.9238795325112867f, -0.9807852804032304f };
constexpr float SP16[16] = {
    0.0000000000000000f,  0.1950903220161282f,  0.3826834323650898f,  0.5555702330196022f,
    0.7071067811865476f,  0.8314696123025452f,  0.9238795325112867f,  0.9807852804032304f,
    1.0000000000000000f,  0.9807852804032304f,  0.9238795325112867f,  0.8314696123025452f,
    0.7071067811865476f,  0.5555702330196022f,  0.3826834323650898f,  0.1950903220161282f };

__device__ __forceinline__ float2 cmul(float2 a, float2 b) {
    return make_float2(a.x*b.x - a.y*b.y, a.x*b.y + a.y*b.x);
}
__device__ __forceinline__ float2 cadd(float2 a, float2 b){ return make_float2(a.x+b.x, a.y+b.y); }
__device__ __forceinline__ float2 csub(float2 a, float2 b){ return make_float2(a.x-b.x, a.y-b.y); }

// LDS bank swizzle (R2-proven: SQ_LDS_BANK_CONFLICT ~ 0).
__device__ __forceinline__ int SW(int e){ return e ^ ((e >> 4) & 15); }

// 16-point DFT in registers, natural order in/out (R2-proven numerics).
template<int SIGN>
__device__ __forceinline__ void dft16(float2 v[16]) {
    const float sgn = (float)SIGN;
    const float C8 = 0.923879532511287f, S8 = 0.382683432365090f, H2 = 0.707106781186548f;
    const float2 w1 = make_float2( C8,  sgn*S8);
    const float2 w2 = make_float2( H2,  sgn*H2);
    const float2 w3 = make_float2( S8,  sgn*C8);
    const float2 w4 = make_float2(0.f,  sgn);
    const float2 w6 = make_float2(-H2,  sgn*H2);
    const float2 w9 = make_float2(-C8, -sgn*S8);
    float2 t[16];
    #pragma unroll
    for (int p = 0; p < 4; ++p) {
        float2 a0 = v[p], a1 = v[p+4], a2 = v[p+8], a3 = v[p+12];
        float2 b0 = cadd(a0,a2), b1 = csub(a0,a2), b2 = cadd(a1,a3), b3 = csub(a1,a3);
        float2 ib3 = make_float2(-sgn*b3.y, sgn*b3.x);   // SIGN*i*b3
        float2 X0 = cadd(b0,b2), X2c = csub(b0,b2);
        float2 X1 = cadd(b1,ib3), X3 = csub(b1,ib3);
        if (p == 1) { X1 = cmul(X1,w1); X2c = cmul(X2c,w2); X3 = cmul(X3,w3); }
        else if (p == 2) { X1 = cmul(X1,w2); X2c = cmul(X2c,w4); X3 = cmul(X3,w6); }
        else if (p == 3) { X1 = cmul(X1,w3); X2c = cmul(X2c,w6); X3 = cmul(X3,w9); }
        t[4*p+0]=X0; t[4*p+1]=X1; t[4*p+2]=X2c; t[4*p+3]=X3;
    }
    #pragma unroll
    for (int q = 0; q < 4; ++q) {
        float2 a0 = t[q], a1 = t[q+4], a2 = t[q+8], a3 = t[q+12];
        float2 b0 = cadd(a0,a2), b1 = csub(a0,a2), b2 = cadd(a1,a3), b3 = csub(a1,a3);
        float2 ib3 = make_float2(-sgn*b3.y, sgn*b3.x);
        v[q+0]  = cadd(b0,b2);
        v[q+8]  = csub(b0,b2);
        v[q+4]  = cadd(b1,ib3);
        v[q+12] = csub(b1,ib3);
    }
}

// v[k] *= e^{i*k*ang}; two independent power chains (depth ~8 not 15).
__device__ __forceinline__ void twiddle16(float2 v[16], float ang) {
    float sn, cs; __sincosf(ang, &sn, &cs);
    float2 w  = make_float2(cs, sn);
    float2 w2 = cmul(w, w);
    float2 to = w;   // odd powers
    float2 te = w2;  // even powers
    v[1] = cmul(v[1], to);
    v[2] = cmul(v[2], te);
    #pragma unroll
    for (int k = 3; k < 16; k += 2) {
        to = cmul(to, w2); v[k] = cmul(v[k], to);
        if (k + 1 < 16) { te = cmul(te, w2); v[k+1] = cmul(v[k+1], te); }
    }
}

// Paired variant: one twiddle-factor chain (same values as twiddle16),
// applied to two register sets. Bit-identical per product to twiddle16.
__device__ __forceinline__ void twiddle16_pair(float2 v0[16], float2 v1[16], float ang) {
    float sn, cs; __sincosf(ang, &sn, &cs);
    float2 w  = make_float2(cs, sn);
    float2 w2 = cmul(w, w);
    float2 to = w;   // odd powers
    float2 te = w2;  // even powers
    v0[1] = cmul(v0[1], to); v1[1] = cmul(v1[1], to);
    v0[2] = cmul(v0[2], te); v1[2] = cmul(v1[2], te);
    #pragma unroll
    for (int k = 3; k < 16; k += 2) {
        to = cmul(to, w2); v0[k] = cmul(v0[k], to); v1[k] = cmul(v1[k], to);
        if (k + 1 < 16) { te = cmul(te, w2); v0[k+1] = cmul(v0[k+1], te); v1[k+1] = cmul(v1[k+1], te); }
    }
}

// Stockham radix-16, 3 stages, single 32KB buffer (R2-proven).
// Input: v[r] = x[tid + 256r]. Output: v[k] = X[tid + 256k].
// Trailing barrier: lds reusable by caller on exit.
template<int SIGN>
__device__ void fft4096_r16(float2 v[16], float2* lds, int tid) {
    dft16<SIGN>(v);
    twiddle16(v, (float)SIGN * 2.0f * PI_F * (float)tid / 4096.0f);
    #pragma unroll
    for (int k = 0; k < 16; ++k) lds[SW(16*tid + k)] = v[k];
    __syncthreads();
    #pragma unroll
    for (int r = 0; r < 16; ++r) v[r] = lds[SW(tid + 256*r)];
    dft16<SIGN>(v);
    twiddle16(v, (float)SIGN * 2.0f * PI_F * (float)(tid >> 4) / 256.0f);
    __syncthreads();                       // in-place: all reads before any write
    {
        const int q = tid & 15, p = tid >> 4;
        #pragma unroll
        for (int k = 0; k < 16; ++k) lds[SW(q + 256*p + 16*k)] = v[k];
    }
    __syncthreads();
    #pragma unroll
    for (int r = 0; r < 16; ++r) v[r] = lds[SW(tid + 256*r)];
    dft16<SIGN>(v);
    __syncthreads();                       // lds reusable by caller
}

// Paired Stockham: two products through two LDS buffers, SHARED barriers.
// Per-product sequence is value-identical to fft4096_r16.
template<int SIGN>
__device__ void fft4096_pair(float2 v0[16], float2 v1[16],
                             float2* lds0, float2* lds1, int tid) {
    dft16<SIGN>(v0);
    dft16<SIGN>(v1);
    twiddle16_pair(v0, v1, (float)SIGN * 2.0f * PI_F * (float)tid / 4096.0f);
    #pragma unroll
    for (int k = 0; k < 16; ++k) {
        const int a = SW(16*tid + k);
        lds0[a] = v0[k]; lds1[a] = v1[k];
    }
    __syncthreads();
    #pragma unroll
    for (int r = 0; r < 16; ++r) {
        const int a = SW(tid + 256*r);
        v0[r] = lds0[a]; v1[r] = lds1[a];
    }
    dft16<SIGN>(v0);
    dft16<SIGN>(v1);
    twiddle16_pair(v0, v1, (float)SIGN * 2.0f * PI_F * (float)(tid >> 4) / 256.0f);
    __syncthreads();                       // in-place: all reads before any write
    {
        const int q = tid & 15, p = tid >> 4;
        #pragma unroll
        for (int k = 0; k < 16; ++k) {
            const int a = SW(q + 256*p + 16*k);
            lds0[a] = v0[k]; lds1[a] = v1[k];
        }
    }
    __syncthreads();
    #pragma unroll
    for (int r = 0; r < 16; ++r) {
        const int a = SW(tid + 256*r);
        v0[r] = lds0[a]; v1[r] = lds1[a];
    }
    dft16<SIGN>(v0);
    dft16<SIGN>(v1);
    __syncthreads();                       // lds reusable by caller
}

// ---- Kernel A: precompute. grid 224 x 256.
// bid 0..31: Hc pair rows (ONE fft of D.(h0 + i*h1), no unpack needed);
// bid 32..95: Gf rows; bid 96..223: Xf rows.
__global__ __launch_bounds__(NT, 2) void ldr_pre_k(
    const float* __restrict__ x, const float* __restrict__ G, const float* __restrict__ H,
    float2* __restrict__ Hc, float2* __restrict__ Gf, float2* __restrict__ Xf)
{
    __shared__ float2 lds[NFFT];
    const int tid = threadIdx.x;
    const int bid = blockIdx.x;
    float2 v[16];
    if (bid < 32) {
        // Hc[p] = fft(D.(H[2p] + i*H[2p+1])) = Hf[2p] + i*Hf[2p+1]
        const float* h0 = H + (size_t)(2*bid)     * NFFT;
        const float* h1 = H + (size_t)(2*bid + 1) * NFFT;
        float sn, cs; __sincosf(PI_F * (float)tid / (float)NFFT, &sn, &cs);
        const float2 dt = make_float2(cs, sn);
        #pragma unroll
        for (int k = 0; k < 16; ++k) {
            const int e = tid + 256*k;
            const float2 d = cmul(dt, make_float2(CP16[k], SP16[k]));  // e^{i*pi*e/N}
            v[k] = cmul(d, make_float2(h0[e], h1[e]));
        }
        fft4096_r16<-1>(v, lds, tid);
        float2* o = Hc + (size_t)bid * NFFT;
        #pragma unroll
        for (int k = 0; k < 16; ++k) o[tid + 256*k] = v[k];
    } else if (bid < 96) {
        const int row = bid - 32;
        const float* g = G + (size_t)row * NFFT;
        #pragma unroll
        for (int k = 0; k < 16; ++k) v[k] = make_float2(g[tid + 256*k], 0.0f);
        fft4096_r16<-1>(v, lds, tid);
        float2* o = Gf + (size_t)row * NFFT;
        #pragma unroll
        for (int k = 0; k < 16; ++k) o[tid + 256*k] = v[k];
    } else {
        const int row = bid - 96;
        const float* xp = x + (size_t)row * NFFT;
        float sn, cs; __sincosf(PI_F * (float)tid / (float)NFFT, &sn, &cs);
        const float2 dt = make_float2(cs, -sn);                        // conj(D) thread part
        #pragma unroll
        for (int k = 0; k < 16; ++k) {
            const int e = tid + 256*k;
            const float2 d = cmul(dt, make_float2(CP16[k], -SP16[k])); // e^{-i*pi*e/N}
            float xv = xp[e];
            v[k] = make_float2(d.x*xv, d.y*xv);
        }
        fft4096_r16<1>(v, lds, tid);
        const float invn = 1.0f / (float)NFFT;
        float2* o = Xf + (size_t)row * NFFT;
        #pragma unroll
        for (int k = 0; k < 16; ++k) o[tid + 256*k] = make_float2(v[k].x*invn, v[k].y*invn);
    }
}

// ---- Kernel B: middle. grid 512 = ip(32) x bpair(16); one rank PAIR and
// TWO batch products per wg, computed SIMULTANEOUSLY (paired ILP).
// Input P = Hc[ip].Xf (hc loaded once, used for both b's). Two paired FFTs,
// shared barriers/twiddles. Hermitian unpack of Z = fft(t0)+i*fft(t1) via
// mirror staged in both LDS buffers; g0/g1 loaded once per e for both Y's.
// Lower-half Y as fp16, DC.x / Nyq.x packed into element 0; plane u = i*2+pr
// (8 planes), row ((u*COUT + j)*BATCH + b), 2048 half2.
__global__ __launch_bounds__(NT, 2) void ldr_mid_k(
    const float2* __restrict__ Hc, const float2* __restrict__ Xf,
    const float2* __restrict__ Gf, __half2* __restrict__ Ph)
{
    __shared__ float2 lds0[NFFT];
    __shared__ float2 lds1[NFFT];
    const int tid = threadIdx.x;
    const int bid = blockIdx.x;         // [0,512)
    const int bp  = bid & 15;           // batch pair index -> b = 2bp, 2bp+1
    const int ip  = bid >> 4;           // ij*2 + pr, [0,32)
    const int pr  = ip & 1;
    const int ij  = ip >> 1;
    const int i   = ij >> 2;            // COUT = 4
    const int j   = ij & 3;
    const int r0  = ij*RANK + 2*pr;     // G rows s0 = r0, s1 = r0+1
    const int b0  = 2*bp;
    const float2* hc = Hc + (size_t)ip * NFFT;
    const float2* x0 = Xf + (size_t)(i*BATCH + b0) * NFFT;
    const float2* x1 = x0 + NFFT;       // b0+1: adjacent row
    const float2* g0 = Gf + (size_t)r0 * NFFT;
    const float2* g1 = g0 + NFFT;
    const int u = i*2 + pr;             // plane in [0,8)

    float2 v0[16], v1[16];
    #pragma unroll
    for (int k = 0; k < 16; ++k) {
        const int e = tid + 256*k;
        const float2 h = hc[e];         // loaded ONCE for both products
        v0[k] = cmul(h, x0[e]);
        v1[k] = cmul(h, x1[e]);
    }
    fft4096_pair<-1>(v0, v1, lds0, lds1, tid);
    {
        // D_e = e^{i*pi*(tid+256k)/4096} = e^{i*pi*tid/4096} * e^{i*pi*k/16}
        float sn, cs; __sincosf(PI_F * (float)tid / (float)NFFT, &sn, &cs);
        const float2 dt = make_float2(cs, sn);
        #pragma unroll
        for (int k = 0; k < 16; ++k) {
            const float2 d = cmul(dt, make_float2(CP16[k], SP16[k]));
            v0[k] = cmul(v0[k], d);
            v1[k] = cmul(v1[k], d);
        }
    }
    fft4096_pair<-1>(v0, v1, lds0, lds1, tid);  // Z = fft(t0)+i*fft(t1); lds free

    // Stage upper halves of both Z's for mirror access.
    #pragma unroll
    for (int k = 8; k < 16; ++k) {
        const int a = SW(tid + 256*k);
        lds0[a] = v0[k]; lds1[a] = v1[k];
    }
    __syncthreads();

    __half2* prow0 = Ph + (size_t)((u*COUT + j)*BATCH + b0) * (NFFT/2);
    __half2* prow1 = prow0 + (NFFT/2);
    #pragma unroll
    for (int k = 0; k < 8; ++k) {
        const int e = tid + 256*k;
        const float2 g0e = g0[e], g1e = g1[e];   // loaded ONCE for both
        const int am = SW(4096 - e);
        // product 0
        {
            const float2 Zk = v0[k];
            const float2 Zm = (e == 0) ? Zk : lds0[am];
            const float2 V1 = make_float2(0.5f*(Zk.x + Zm.x), 0.5f*(Zk.y - Zm.y));
            const float2 V2 = make_float2(0.5f*(Zk.y + Zm.y), 0.5f*(Zm.x - Zk.x));
            float2 Y = cadd(cmul(g0e, V1), cmul(g1e, V2));
            if (k == 0 && tid == 0) {
                const float2 Zn = v0[8];
                const float Ynyq = g0[2048].x * Zn.x + g1[2048].x * Zn.y;
                Y = make_float2(Y.x, Ynyq);      // pack DC.x / Nyq.x
            }
            prow0[e] = __floats2half2_rn(Y.x, Y.y);
        }
        // product 1
        {
            const float2 Zk = v1[k];
            const float2 Zm = (e == 0) ? Zk : lds1[am];
            const float2 V1 = make_float2(0.5f*(Zk.x + Zm.x), 0.5f*(Zk.y - Zm.y));
            const float2 V2 = make_float2(0.5f*(Zk.y + Zm.y), 0.5f*(Zm.x - Zk.x));
            float2 Y = cadd(cmul(g0e, V1), cmul(g1e, V2));
            if (k == 0 && tid == 0) {
                const float2 Zn = v1[8];
                const float Ynyq = g0[2048].x * Zn.x + g1[2048].x * Zn.y;
                Y = make_float2(Y.x, Ynyq);      // pack DC.x / Nyq.x
            }
            prow1[e] = __floats2half2_rn(Y.x, Y.y);
        }
    }
}

// ---- Kernel C: final (R11 shape). grid 128 = (j,b). Sum 8 fp16 half-rows
// via int4 loads, conjugate-mirror upper half, one inverse FFT, write Re/N.
__global__ __launch_bounds__(NT, 2) void ldr_fin_k(
    const __half2* __restrict__ Ph, float* __restrict__ out)
{
    __shared__ float2 lds[NFFT];
    __shared__ float2 sh[NFFT/2];      // summed half-spectrum (packed elem 0)
    const int tid = threadIdx.x;
    const int bid = blockIdx.x;        // j*BATCH + b
    const int b = bid & (BATCH - 1);
    const int j = bid >> 5;

    float2 a[8];
    #pragma unroll
    for (int k = 0; k < 8; ++k) a[k] = make_float2(0.f, 0.f);
    #pragma unroll
    for (int u = 0; u < 8; ++u) {
        const int4* row4 = (const int4*)(Ph + (size_t)((u*COUT + j)*BATCH + b) * (NFFT/2));
        #pragma unroll
        for (int c = 0; c < 2; ++c) {
            const int4 w = row4[tid + 256*c];
            const int ww[4] = { w.x, w.y, w.z, w.w };
            #pragma unroll
            for (int r = 0; r < 4; ++r) {
                __half2 h = *(const __half2*)&ww[r];
                float2 f = __half22float2(h);
                a[c*4+r] = cadd(a[c*4+r], f);
            }
        }
    }
    float4* sh4 = (float4*)sh;
    #pragma unroll
    for (int c = 0; c < 2; ++c) {
        sh4[2*(tid + 256*c) + 0] = make_float4(a[c*4+0].x, a[c*4+0].y, a[c*4+1].x, a[c*4+1].y);
        sh4[2*(tid + 256*c) + 1] = make_float4(a[c*4+2].x, a[c*4+2].y, a[c*4+3].x, a[c*4+3].y);
    }
    __syncthreads();

    const float dc  = sh[0].x;
    const float nyq = sh[0].y;
    float2 v[16];
    #pragma unroll
    for (int k = 0; k < 8; ++k) v[k] = sh[tid + 256*k];
    if (tid == 0) v[0] = make_float2(dc, 0.0f);
    #pragma unroll
    for (int k = 8; k < 16; ++k) {
        const int m = 4096 - (tid + 256*k);          // mirror index in [1,2048]
        if (m == 2048) {                              // only tid==0, k==8
            v[k] = make_float2(nyq, 0.0f);
        } else {
            float2 c = sh[m];
            v[k] = make_float2(c.x, -c.y);            // conj
        }
    }
    // no barrier needed: fft writes lds[], sh[] untouched
    fft4096_r16<1>(v, lds, tid);
    const float invn = 1.0f / (float)NFFT;
    float* orow = out + (size_t)bid * NFFT;
    #pragma unroll
    for (int k = 0; k < 16; ++k) orow[tid + 256*k] = v[k].x * invn;
}

extern "C" void kernel_launch(void* const* d_in, const int* in_sizes, int n_in,
                              void* d_out, int out_size, void* d_ws, size_t ws_size,
                              hipStream_t stream) {
    const float* x = (const float*)d_in[0];   // (CIN, B, N)
    const float* G = (const float*)d_in[1];   // (CIN, COUT, R, N)
    const float* H = (const float*)d_in[2];   // (CIN, COUT, R, N)
    float* out = (float*)d_out;               // (COUT, B, N)

    float2*  Hc = (float2*)d_ws;                    // 32 packed pair rows (1 MB)
    float2*  Gf = Hc + (size_t)32 * NFFT;           // 64 rows (2 MB)
    float2*  Xf = Gf + (size_t)64 * NFFT;           // 128 rows (4 MB)
    __half2* Ph = (__half2*)(Xf + (size_t)128 * NFFT); // 1024 half-rows x 2048 h2 (8 MB)

    ldr_pre_k<<<224, NT, 0, stream>>>(x, G, H, Hc, Gf, Xf);
    ldr_mid_k<<<512, NT, 0, stream>>>(Hc, Xf, Gf, Ph);   // 512 = ip(32) x bpair(16)
    ldr_fin_k<<<COUT * BATCH, NT, 0, stream>>>(Ph, out);
}